// Round 9
// baseline (57.747 us; speedup 1.0000x reference)
//
#include <hip/hip_runtime.h>
#include <hip/hip_bf16.h>
#include <math.h>

// B=64, C=3, H=W=512.
// out[b,0] = sigmoid( sum_{c,h,w} x[b,c,h,w] * M_col[h,w] / C )
// out[b,1] = sigmoid( sum_{c,h,w} x[b,c,h,w] * M_row[h,w] / C )
// M_row = (1/HW) D^T (diag(rw) A) D ;  M_col = (1/HW) D^T (A diag(cw)) D
// D = orthonormal DCT-II, DT[n][k] = D[k][n] computed IN-REGISTER (no tables).
//
// Structural rules learned (R2-R8):
//  - NO same-address device atomics / fences in the 2048-block streamer
//    (R3/R4: ~100+ us serialized tail).
//  - NO __builtin_nontemporal_load on the x stream (R3: latency-bound crawl).
//  - EVERY phase needs >=16 waves/CU (R2: 8 waves/CU streamer 3x slower;
//    R6: 4 waves/CU cooperative GEMM +60us).
//  - kc load-slot/pipeline-depth tweaks are neutral (R7/R8): kc is at its
//    floor; remaining fat is the serial prep chain -> eliminate launches.

typedef __attribute__((ext_vector_type(8))) short bf16x8;
typedef __attribute__((ext_vector_type(4))) float f32x4;

#define NFULL 512
#define HWTOT 262144
#define SCALE_M (1.0f / 786432.0f)      // 1/(H*W*C)
#define KC_BLOCKS 2048
#define S0 0.04419417382415922f         // sqrt(1/512)
#define S1 0.0625f                      // sqrt(2/512)

static __device__ __forceinline__ unsigned short f_to_bf16(float f) {
  union { float f; unsigned int i; } v; v.f = f;
  unsigned int r = v.i + 0x7FFFu + ((v.i >> 16) & 1u);   // round-nearest-even
  return (unsigned short)(r >> 16);
}
static __device__ __forceinline__ float bf_lo(unsigned int u) {
  union { unsigned int i; float f; } v; v.i = u << 16; return v.f;
}
static __device__ __forceinline__ float bf_hi(unsigned int u) {
  union { unsigned int i; float f; } v; v.i = u & 0xFFFF0000u; return v.f;
}

// DT[r][c] = s_c * cos(pi*(r+0.5)*c/512); 8 consecutive cols from cbase.
static __device__ __forceinline__ bf16x8 dct_frag(int r, int cbase) {
  unsigned int st = (unsigned int)(2 * r + 1);
  unsigned int pb = st * (unsigned int)cbase;
  bf16x8 v;
#pragma unroll
  for (int j = 0; j < 8; ++j) {
    unsigned int ph = (pb + (unsigned int)j * st) & 2047u;
    float s = ((cbase + j) == 0) ? S0 : S1;
    v[j] = (short)f_to_bf16(s * cospif((float)ph * (1.0f / 1024.0f)));
  }
  return v;
}

// ---------------- KA2: T1 = (diag(rw)A)@D, T2 = (A diag(cw))@D ----------------
// att read as fp32; DT B-frags via in-register trig. Split-K x4, 1024 blocks.
// T1T[w][k], T2T[w][k] transposed bf16 outputs.
__global__ __launch_bounds__(256) void ka2(const float* __restrict__ att,
                                           const float* __restrict__ rw,
                                           const float* __restrict__ cw,
                                           unsigned short* __restrict__ T1T,
                                           unsigned short* __restrict__ T2T) {
  __shared__ f32x4 r1[4][64];
  __shared__ f32x4 r2[4][64];
  int tile = blockIdx.x;               // 0..1023
  int tk = tile >> 5, tw = tile & 31;
  int tid = threadIdx.x, lane = tid & 63, wv = tid >> 6;
  int l16 = lane & 15;
  int koff = (lane >> 4) * 8;
  int row_a = tk * 16 + l16;           // att row (k index)
  int row_b = tw * 16 + l16;           // DT row (w index)
  int l0beg = wv * 128;                // this wave's K chunk
  float rwa = rw[row_a];

  f32x4 acc1 = {0.f, 0.f, 0.f, 0.f};
  f32x4 acc2 = {0.f, 0.f, 0.f, 0.f};
#pragma unroll
  for (int l0 = 0; l0 < 128; l0 += 32) {
    int cbase = l0beg + l0 + koff;
    const f32x4* ap = (const f32x4*)(att + row_a * NFULL + cbase);
    f32x4 av0 = ap[0], av1 = ap[1];
    const f32x4* cp = (const f32x4*)(cw + cbase);
    f32x4 cw0 = cp[0], cw1 = cp[1];
    bf16x8 a1, a2;
    float av[8] = {av0.x, av0.y, av0.z, av0.w, av1.x, av1.y, av1.z, av1.w};
    float cv[8] = {cw0.x, cw0.y, cw0.z, cw0.w, cw1.x, cw1.y, cw1.z, cw1.w};
#pragma unroll
    for (int j = 0; j < 8; ++j) {
      a1[j] = (short)f_to_bf16(av[j] * rwa);
      a2[j] = (short)f_to_bf16(av[j] * cv[j]);
    }
    bf16x8 b = dct_frag(row_b, cbase);
    acc1 = __builtin_amdgcn_mfma_f32_16x16x32_bf16(a1, b, acc1, 0, 0, 0);
    acc2 = __builtin_amdgcn_mfma_f32_16x16x32_bf16(a2, b, acc2, 0, 0, 0);
  }
  r1[wv][lane] = acc1;
  r2[wv][lane] = acc2;
  __syncthreads();
  if (wv == 0) {
    f32x4 s1 = (r1[0][lane] + r1[1][lane]) + (r1[2][lane] + r1[3][lane]);
    f32x4 s2 = (r2[0][lane] + r2[1][lane]) + (r2[2][lane] + r2[3][lane]);
    int col = lane & 15, r0 = (lane >> 4) * 4;
    int w  = tw * 16 + col;
    int k0 = tk * 16 + r0;
    unsigned int g0 = f_to_bf16(s1[0]) | ((unsigned int)f_to_bf16(s1[1]) << 16);
    unsigned int g1 = f_to_bf16(s1[2]) | ((unsigned int)f_to_bf16(s1[3]) << 16);
    unsigned int c0 = f_to_bf16(s2[0]) | ((unsigned int)f_to_bf16(s2[1]) << 16);
    unsigned int c1 = f_to_bf16(s2[2]) | ((unsigned int)f_to_bf16(s2[3]) << 16);
    *(uint2*)(T1T + w * NFULL + k0) = make_uint2(g0, g1);
    *(uint2*)(T2T + w * NFULL + k0) = make_uint2(c0, c1);
  }
}

// ---------------- KB2: M = D^T @ T1/T2 ; DT A-frags in-register; packed bf16 out ----
// Mpk[h*512+w] = bf16(Mcol) | bf16(Mrow)<<16
__global__ __launch_bounds__(256) void kb2(const unsigned short* __restrict__ T1T,
                                           const unsigned short* __restrict__ T2T,
                                           unsigned int* __restrict__ Mpk) {
  __shared__ f32x4 r1[4][64];
  __shared__ f32x4 r2[4][64];
  int tile = blockIdx.x;
  int th = tile >> 5, tw = tile & 31;
  int tid = threadIdx.x, lane = tid & 63, wv = tid >> 6;
  int l16 = lane & 15;
  int koff = (lane >> 4) * 8;
  int row_a = th * 16 + l16;           // DT row (h index)
  int row_b = tw * 16 + l16;           // T^T row (w index)
  int k0beg = wv * 128;

  const bf16x8* Rp = (const bf16x8*)(T1T + row_b * NFULL);
  const bf16x8* Cp = (const bf16x8*)(T2T + row_b * NFULL);

  f32x4 accR = {0.f, 0.f, 0.f, 0.f};
  f32x4 accC = {0.f, 0.f, 0.f, 0.f};
#pragma unroll
  for (int k0 = 0; k0 < 128; k0 += 32) {
    int cbase = k0beg + k0 + koff;
    int e = cbase >> 3;
    bf16x8 a = dct_frag(row_a, cbase);
    accR = __builtin_amdgcn_mfma_f32_16x16x32_bf16(a, Rp[e], accR, 0, 0, 0);
    accC = __builtin_amdgcn_mfma_f32_16x16x32_bf16(a, Cp[e], accC, 0, 0, 0);
  }
  r1[wv][lane] = accR;
  r2[wv][lane] = accC;
  __syncthreads();
  if (wv == 0) {
    f32x4 sR = (r1[0][lane] + r1[1][lane]) + (r1[2][lane] + r1[3][lane]);
    f32x4 sC = (r2[0][lane] + r2[1][lane]) + (r2[2][lane] + r2[3][lane]);
    int col = lane & 15, r0 = (lane >> 4) * 4;
    int h0 = th * 16 + r0;
    int w  = tw * 16 + col;
#pragma unroll
    for (int j = 0; j < 4; ++j) {
      Mpk[(h0 + j) * NFULL + w] =
          (unsigned int)f_to_bf16(sC[j] * SCALE_M) |
          ((unsigned int)f_to_bf16(sR[j] * SCALE_M) << 16);
    }
  }
}

// ---------------- KC: stream x once; 4 loads/iter, 3-slot distance-2 pipeline ----
__global__ __launch_bounds__(256, 6) void kc_dot(const float* __restrict__ x,
                                                 const unsigned int* __restrict__ Mpk,
                                                 float* __restrict__ partial) {
  int b   = blockIdx.x >> 5;
  int sub = blockIdx.x & 31;
  int tid = threadIdx.x;
  const f32x4* __restrict__ xp = (const f32x4*)x + (size_t)b * 196608;
  const uint4* __restrict__ mp4 = (const uint4*)Mpk;   // 4 hw elems per uint4

  int base = sub * 2048 + tid;

  uint4 mp[3];
  f32x4 xs0[3], xs1[3], xs2[3];
#define LOADIT(s, it)                                   \
  {                                                     \
    int i_ = base + (it) * 256;                         \
    mp[s]  = mp4[i_];                                   \
    xs0[s] = xp[i_];                                    \
    xs1[s] = xp[i_ + 65536];                            \
    xs2[s] = xp[i_ + 131072];                           \
  }
  LOADIT(0, 0)
  LOADIT(1, 1)
  LOADIT(2, 2)

  float a0 = 0.f, a1 = 0.f;
#pragma unroll
  for (int it = 0; it < 8; ++it) {
    int s = it % 3;                    // compile-time after full unroll
    f32x4 sv = (xs0[s] + xs1[s]) + xs2[s];
    uint4 m = mp[s];
    if (it + 3 < 8) LOADIT(s, it + 3)
    a0 += sv.x * bf_lo(m.x) + sv.y * bf_lo(m.y) + sv.z * bf_lo(m.z) + sv.w * bf_lo(m.w);
    a1 += sv.x * bf_hi(m.x) + sv.y * bf_hi(m.y) + sv.z * bf_hi(m.z) + sv.w * bf_hi(m.w);
  }
#undef LOADIT

  int lane = tid & 63, wv = tid >> 6;
#pragma unroll
  for (int off = 32; off > 0; off >>= 1) {
    a0 += __shfl_down(a0, off);
    a1 += __shfl_down(a1, off);
  }
  __shared__ float red[8];
  if (lane == 0) { red[wv * 2] = a0; red[wv * 2 + 1] = a1; }
  __syncthreads();
  if (tid == 0) {
    float s0 = red[0] + red[2] + red[4] + red[6];
    float s1 = red[1] + red[3] + red[5] + red[7];
    partial[(b * 32 + sub) * 2 + 0] = s0;
    partial[(b * 32 + sub) * 2 + 1] = s1;
  }
}

// ---------------- KD: final deterministic reduce + sigmoid ----------------
__global__ void kd_final(const float* __restrict__ partial, float* __restrict__ out) {
  int t = threadIdx.x;           // 0..127 -> (b, o)
  int b = t >> 1, o = t & 1;
  float s = 0.f;
#pragma unroll
  for (int j = 0; j < 32; ++j) s += partial[(b * 32 + j) * 2 + o];
  out[b * 2 + o] = 1.0f / (1.0f + expf(-s));
}

extern "C" void kernel_launch(void* const* d_in, const int* in_sizes, int n_in,
                              void* d_out, int out_size, void* d_ws, size_t ws_size,
                              hipStream_t stream) {
  const float* x   = (const float*)d_in[0];   // [64,3,512,512]
  const float* att = (const float*)d_in[1];   // [512,512]
  const float* rw  = (const float*)d_in[2];   // [512]
  const float* cw  = (const float*)d_in[3];   // [512]
  float* out = (float*)d_out;                 // [64,2]

  // workspace layout (~2.1 MiB)
  unsigned short* T1T = (unsigned short*)d_ws;        // 512 KB
  unsigned short* T2T = T1T + HWTOT;                  // 512 KB
  unsigned int*  Mpk  = (unsigned int*)(T2T + HWTOT); // 1 MB
  float* partial = (float*)(Mpk + HWTOT);             // 16 KB

  ka2<<<1024, 256, 0, stream>>>(att, rw, cw, T1T, T2T);
  kb2<<<1024, 256, 0, stream>>>(T1T, T2T, Mpk);
  kc_dot<<<KC_BLOCKS, 256, 0, stream>>>(x, Mpk, partial);
  kd_final<<<1, 128, 0, stream>>>(partial, out);
}